// Round 1
// baseline (30.658 us; speedup 1.0000x reference)
//
#include <hip/hip_runtime.h>

// Problem constants (match reference)
#define B_TOTAL 16777216
#define NSTEPS 64

// Kernel 1: one block of 64 threads.
//   gammas[i] = sigmoid(raw_gammas[i])  -> written to out_gammas (d_out tail)
//   surv      = prod_i (1 - gammas[i])  -> written to d_ws[0]
__global__ void qm_gamma_kernel(const float* __restrict__ raw_gammas,
                                float* __restrict__ out_gammas,
                                float* __restrict__ surv_out) {
    const int lane = threadIdx.x;  // 0..63, one wave
    float rg = raw_gammas[lane];
    // accurate sigmoid
    float g = 1.0f / (1.0f + expf(-rg));
    out_gammas[lane] = g;
    float v = 1.0f - g;
    // 64-lane product reduction (wave = 64 on CDNA)
    #pragma unroll
    for (int off = 32; off > 0; off >>= 1) {
        v *= __shfl_xor(v, off, 64);
    }
    if (lane == 0) {
        surv_out[0] = v;
    }
}

// Kernel 2: streaming elementwise, float4-vectorized, grid-stride.
//   out[i] = cos(thetas[i]) * surv + (1 - surv)
__global__ void qm_expval_kernel(const float* __restrict__ thetas,
                                 const float* __restrict__ surv_ptr,
                                 float* __restrict__ out) {
    const float surv = surv_ptr[0];          // uniform scalar, L2-cached
    const float oms = 1.0f - surv;

    const float4* __restrict__ t4 = reinterpret_cast<const float4*>(thetas);
    float4* __restrict__ o4 = reinterpret_cast<float4*>(out);
    const int n4 = B_TOTAL / 4;

    int idx = blockIdx.x * blockDim.x + threadIdx.x;
    const int stride = gridDim.x * blockDim.x;

    for (int i = idx; i < n4; i += stride) {
        float4 t = t4[i];
        float4 r;
        r.x = fmaf(cosf(t.x), surv, oms);
        r.y = fmaf(cosf(t.y), surv, oms);
        r.z = fmaf(cosf(t.z), surv, oms);
        r.w = fmaf(cosf(t.w), surv, oms);
        o4[i] = r;
    }
}

extern "C" void kernel_launch(void* const* d_in, const int* in_sizes, int n_in,
                              void* d_out, int out_size, void* d_ws, size_t ws_size,
                              hipStream_t stream) {
    const float* thetas = (const float*)d_in[0];
    // d_in[1] = phis: unused (RZ does not change <Z>)
    const float* raw_gammas = (const float*)d_in[2];

    float* out_expvals = (float*)d_out;              // [B_TOTAL]
    float* out_gammas = (float*)d_out + B_TOTAL;     // [NSTEPS]
    float* surv = (float*)d_ws;                      // scalar scratch

    // Stage 1: gammas + survival product (tiny)
    qm_gamma_kernel<<<1, 64, 0, stream>>>(raw_gammas, out_gammas, surv);

    // Stage 2: streaming expvals. ~2048 blocks x 256 threads, grid-stride.
    const int block = 256;
    const int grid = 2048;
    qm_expval_kernel<<<grid, block, 0, stream>>>(thetas, surv, out_expvals);
}

// Round 2
// 26.990 us; speedup vs baseline: 1.1359x; 1.1359x over previous
//
#include <hip/hip_runtime.h>

// Problem constants (match reference)
#define B_TOTAL 16777216
#define NSTEPS 64

// Fused kernel:
//  - Every block computes surv = prod(1 - sigmoid(raw_gammas)) itself
//    (64 lanes of wave 0 + LDS broadcast; raw_gammas is 256 B, L2-hot).
//  - Block 0 additionally writes gammas to the output tail.
//  - Then all threads stream thetas -> expvals with float4, grid-stride.
__global__ void __launch_bounds__(256) qm_fused_kernel(
        const float* __restrict__ thetas,
        const float* __restrict__ raw_gammas,
        float* __restrict__ out_expvals,
        float* __restrict__ out_gammas) {
    __shared__ float s_surv;
    const int tid = threadIdx.x;

    if (tid < 64) {  // one full wave
        float rg = raw_gammas[tid];
        float g = 1.0f / (1.0f + __expf(-rg));
        if (blockIdx.x == 0) {
            out_gammas[tid] = g;
        }
        float v = 1.0f - g;
        #pragma unroll
        for (int off = 32; off > 0; off >>= 1) {
            v *= __shfl_xor(v, off, 64);
        }
        if (tid == 0) s_surv = v;
    }
    __syncthreads();

    const float surv = s_surv;
    const float oms = 1.0f - surv;

    const float4* __restrict__ t4 = reinterpret_cast<const float4*>(thetas);
    float4* __restrict__ o4 = reinterpret_cast<float4*>(out_expvals);
    const int n4 = B_TOTAL / 4;  // 4,194,304

    int idx = blockIdx.x * blockDim.x + threadIdx.x;
    const int stride = gridDim.x * blockDim.x;  // 524,288 -> exactly 8 iters

    #pragma unroll 4
    for (int i = idx; i < n4; i += stride) {
        float4 t = t4[i];
        float4 r;
        r.x = fmaf(__cosf(t.x), surv, oms);
        r.y = fmaf(__cosf(t.y), surv, oms);
        r.z = fmaf(__cosf(t.z), surv, oms);
        r.w = fmaf(__cosf(t.w), surv, oms);
        o4[i] = r;
    }
}

extern "C" void kernel_launch(void* const* d_in, const int* in_sizes, int n_in,
                              void* d_out, int out_size, void* d_ws, size_t ws_size,
                              hipStream_t stream) {
    const float* thetas = (const float*)d_in[0];
    // d_in[1] = phis: unused (RZ does not change <Z>)
    const float* raw_gammas = (const float*)d_in[2];

    float* out_expvals = (float*)d_out;              // [B_TOTAL]
    float* out_gammas = (float*)d_out + B_TOTAL;     // [NSTEPS]

    const int block = 256;
    const int grid = 2048;  // 8 blocks/CU, grid-stride covers 16.7M elems
    qm_fused_kernel<<<grid, block, 0, stream>>>(thetas, raw_gammas,
                                                out_expvals, out_gammas);
}